// Round 6
// baseline (354.488 us; speedup 1.0000x reference)
//
#include <hip/hip_runtime.h>
#include <hip/hip_cooperative_groups.h>
#include <math.h>

namespace cg = cooperative_groups;

typedef unsigned short u16;
typedef unsigned int   u32;

#define B_       64
#define NN_      64
#define HL_      50
#define IN_DIM   384
#define POS_DIM  64
#define ATT_DIM  256
#define NEWS_DIM 448   // IN_DIM + POS_DIM

typedef __attribute__((ext_vector_type(8))) short short8;   // bf16x8 MFMA frag
typedef __attribute__((ext_vector_type(4))) float f32x4;    // MFMA acc

#if __has_builtin(__builtin_amdgcn_exp2f)
#define EXP2F(x) __builtin_amdgcn_exp2f(x)
#else
#define EXP2F(x) exp2f(x)
#endif
#if __has_builtin(__builtin_amdgcn_rcpf)
#define RCPF(x) __builtin_amdgcn_rcpf(x)
#else
#define RCPF(x) (1.0f/(x))
#endif

__device__ __forceinline__ u16 f2bf(float f) {
    union { float f; u32 i; } v; v.f = f;
    u32 r = v.i + 0x7fffu + ((v.i >> 16) & 1u);   // RNE
    return (u16)(r >> 16);
}
__device__ __forceinline__ float bf2f(u16 u) {
    union { u32 i; float f; } v; v.i = ((u32)u) << 16; return v.f;
}
__device__ __forceinline__ uint2 pack4(float4 v) {
    return make_uint2((u32)f2bf(v.x) | ((u32)f2bf(v.y) << 16),
                      (u32)f2bf(v.z) | ((u32)f2bf(v.w) << 16));
}
// tanh(x) = 1 - 2/(1+2^(x*2*log2e)); v_exp+v_rcp saturate correctly at +-inf.
__device__ __forceinline__ float fast_tanh(float x) {
    float e = EXP2F(x * 2.88539008f);
    return 1.0f - 2.0f * RCPF(1.0f + e);
}

// ---- phase P body (byte-equivalent to R4 prep_k, virtual-block form) ----
__device__ __forceinline__ void prep_body(
    u32 bid, u32 tid,
    const float* __restrict__ W1, const float* __restrict__ newsv,
    const float* __restrict__ logv, const float* __restrict__ pos,
    u16* __restrict__ Wbf, u16* __restrict__ nv_bf, u16* __restrict__ lf_bf,
    float* __restrict__ nf)
{
    if (bid < 2936u) {
        u32 x = bid & 7u, j = bid >> 3;
        if (j < 192u) {            // newsv rows [512x, 512x+512) -> nv_bf + nf
            u32 idx = j * 256u + tid;              // < 49152
            u32 r = 512u * x + idx / 96u, d4 = idx % 96u;
            float4 v = *(const float4*)(newsv + (size_t)r * IN_DIM + d4 * 4u);
            *(uint2*)(nv_bf + (size_t)r * IN_DIM + d4 * 4u) = pack4(v);
            *(float4*)(nf + (size_t)r * NEWS_DIM + d4 * 4u) = v;
        } else if (j < 342u) {     // logv rows [400x, 400x+400) -> lf_bf head
            u32 idx = (j - 192u) * 256u + tid;     // < 38400
            u32 r = 400u * x + idx / 96u, d4 = idx % 96u;
            float4 v = *(const float4*)(logv + (size_t)r * IN_DIM + d4 * 4u);
            *(uint2*)(lf_bf + (size_t)r * NEWS_DIM + d4 * 4u) = pack4(v);
        } else {                   // pos tail, lf rows [400x, 400x+400)
            u32 idx = (j - 342u) * 256u + tid;     // < 6400
            u32 r = 400u * x + idx / 16u, d4 = idx % 16u;
            u32 h = r % HL_;
            float4 v = *(const float4*)(pos + (size_t)(1u + h) * POS_DIM + d4 * 4u);
            *(uint2*)(lf_bf + (size_t)r * NEWS_DIM + IN_DIM + d4 * 4u) = pack4(v);
        }
        return;
    }
    bid -= 2936u;
    if (bid < 224u) {              // W1 -> Wbf (read-shared; placement moot)
        u32 i = bid * 256u + tid;
        float4 v = *(const float4*)(W1 + (size_t)i * 4u);
        *(uint2*)(Wbf + (size_t)i * 4u) = pack4(v);
        return;
    }
    bid -= 224u;
    {                              // nf zero tail (no downstream reader)
        u32 i = bid * 256u + tid;  // < 65536
        u32 r = i / 16u, d4 = i % 16u;
        *(float4*)(nf + (size_t)r * NEWS_DIM + IN_DIM + d4 * 4u) =
            make_float4(0.f, 0.f, 0.f, 0.f);
    }
}

// ---------------- R16: ONE cooperative kernel = prep | sync | gemm | sync
// | attn. Rationale: per-kernel counters bound all our kernels well under
// the top-5 cutoff each round, yet totals sit ~70us above their sum --
// consistent with the 256MiB ws re-poison fill (~45us, untouchable) plus
// ~20-25us of launch gaps (touchable). Fusion collapses the gaps to two
// grid.sync()s and removes the kernel-boundary L2 writeback/invalidate
// between producer and consumer phases (candidate explanation for why
// cross-kernel XCD alignment was twice a null).
// All three phase bodies are byte-equivalent to R4's proven kernels.
// 1024 blocks x 256 thr; virtual-block stride 1024 == 0 mod 8 keeps the
// XCD alignment of every phase intact.
__global__ __launch_bounds__(256, 4) void fused_k(
    const float* __restrict__ W1, const float* __restrict__ newsv,
    const float* __restrict__ logv, const float* __restrict__ pos,
    const int* __restrict__ lmask, const float* __restrict__ w2,
    const float* __restrict__ b1,
    u16* __restrict__ Wbf, u16* __restrict__ nv_bf, u16* __restrict__ lf_bf,
    float* __restrict__ nf, float* __restrict__ pn, float* __restrict__ plT,
    float* __restrict__ out)
{
    __shared__ float at_s[4][64];              // attn phase, 1 KB
    u32 bid = blockIdx.x;                      // [0,1024)
    u32 tid = threadIdx.x;
    int lane = (int)(tid & 63u);
    int wid  = __builtin_amdgcn_readfirstlane((int)(tid >> 6));   // 0..3

    // ---- phase P: prep (3416 virtual blocks, stride 1024) ----
    for (u32 vb = bid; vb < 3416u; vb += 1024u)
        prep_body(vb, tid, W1, newsv, logv, pos, Wbf, nv_bf, lf_bf, nf);

    cg::this_grid().sync();

    // ---- phase G: gemm, 1824 tiles = 456 blocks x 4 waves ----
    // bid = 8k+x (k<57): wave wid handles R4 tile j = 4k+wid on XCD x.
    if (bid < 456u) {
        int x = (int)(bid & 7u), j = (int)((bid >> 3) * 4u) + wid;
        int m = lane & 15, q = lane >> 4;
        bool is_pn = j < 128;
        int r0, c0, lda, koff, klen;
        const u16* A;
        if (is_pn) {               // 16 tiles per b: 4 row-bands x 4 col-tiles
            int b = x * 8 + (j >> 4);
            r0 = b * 64 + ((j >> 2) & 3) * 16;
            c0 = (j & 3) * 64;
            A = nv_bf; lda = IN_DIM;   koff = 0;        klen = IN_DIM;
        } else {                   // 100 tiles: 25 row-bands x 4 col-tiles
            int j2 = j - 128;
            r0 = 400 * x + (j2 >> 2) * 16;
            c0 = (j2 & 3) * 64;
            A = lf_bf; lda = NEWS_DIM; koff = NEWS_DIM; klen = NEWS_DIM;
        }

        f32x4 acc[4];
#pragma unroll
        for (int b = 0; b < 4; b++) acc[b] = (f32x4){0.f, 0.f, 0.f, 0.f};

        const u16* Ap = A + (size_t)(r0 + m) * lda + q * 8;
        const u16* Wp = Wbf + (size_t)(c0 + m) * (2 * NEWS_DIM) + koff + q * 8;

        for (int k = 0; k < klen; k += 32) {
            short8 af, wf[4];
            af = *(const short8*)(Ap + k);
#pragma unroll
            for (int ct = 0; ct < 4; ct++)
                wf[ct] = *(const short8*)(Wp + ct * 16 * (2 * NEWS_DIM) + k);
#pragma unroll
            for (int ct = 0; ct < 4; ct++)
                acc[ct] = __builtin_amdgcn_mfma_f32_16x16x32_bf16(af, wf[ct], acc[ct], 0, 0, 0);
        }
        // C/D layout: col = lane&15, row = (lane>>4)*4 + i  [m89]
#pragma unroll
        for (int ct = 0; ct < 4; ct++)
#pragma unroll
            for (int i = 0; i < 4; i++) {
                int gr = r0 + q * 4 + i;
                int gc = c0 + ct * 16 + m;
                float v = acc[ct][i];
                if (is_pn) {
                    pn[(size_t)gr * ATT_DIM + gc] = v + b1[gc];
                } else {
                    int bb = gr / HL_, hh = gr - bb * HL_;
                    plT[(size_t)(bb * ATT_DIM + gc) * HL_ + hh] = v;
                }
            }
    }

    cg::this_grid().sync();

    // ---- phase A: attn (R4 body, 1024 blocks x 4 waves) ----
    {
        int x     = (int)(bid & 7u);           // XCD id
        int local = (int)(bid >> 3);           // [0,128)
        int b     = x * 8 + (local >> 4);      // 8 b's per XCD
        int sub   = local & 15;                // 16 blocks per b
        int g     = b * 64 + sub * 4 + wid;    // uniform (SGPR)
        int n_hl  = (lane < HL_) ? lane : (HL_ - 1);
        const float* pr = pn + (size_t)g * ATT_DIM;    // uniform -> s_load
        const float* pl = plT + (size_t)b * ATT_DIM * HL_ + n_hl;

        float a0 = 0.f, a1 = 0.f, a2 = 0.f, a3 = 0.f;
#pragma unroll 4
        for (int a = 0; a < ATT_DIM; a += 4) {
            float4 w4 = *(const float4*)(w2 + a);  // uniform -> s_load
            float4 p  = *(const float4*)(pr + a);  // uniform -> s_load
            float l0 = pl[(a + 0) * HL_];
            float l1 = pl[(a + 1) * HL_];
            float l2 = pl[(a + 2) * HL_];
            float l3 = pl[(a + 3) * HL_];
            a0 = __builtin_fmaf(fast_tanh(p.x + l0), w4.x, a0);
            a1 = __builtin_fmaf(fast_tanh(p.y + l1), w4.y, a1);
            a2 = __builtin_fmaf(fast_tanh(p.z + l2), w4.z, a2);
            a3 = __builtin_fmaf(fast_tanh(p.w + l3), w4.w, a3);
        }
        float acc = (a0 + a1) + (a2 + a3);
        int mv = (lane < HL_) ? lmask[b * HL_ + lane] : 0;
        float logit = mv ? acc : -1e9f;        // b2 dropped: softmax-invariant
        float mx = logit;
#pragma unroll
        for (int o = 32; o > 0; o >>= 1) mx = fmaxf(mx, __shfl_xor(mx, o));
        float e = EXP2F((logit - mx) * 1.44269504f);   // masked lanes -> 0
        float s = e;
#pragma unroll
        for (int o = 32; o > 0; o >>= 1) s += __shfl_xor(s, o);
        at_s[wid][lane] = e * RCPF(s);
        // no barrier: same wave writes & reads its own slice

        // phase 2: packed u32 bf16 loads; lane covers d-pairs
        // {2l,2l+1}+128j (j<3) + tail 384+2*(l&31) (stored by lanes<32).
        const u32* lfb32 = (const u32*)(lf_bf + (size_t)b * HL_ * NEWS_DIM);
        int tidx = 192 + (lane & 31);
        float p0 = 0.f, p1 = 0.f, p2 = 0.f, p3 = 0.f,
              p4 = 0.f, p5 = 0.f, p6 = 0.f, p7 = 0.f;
        for (int h = 0; h < HL_; h++) {
            float av = at_s[wid][h];           // LDS broadcast
            const u32* r32 = lfb32 + h * (NEWS_DIM / 2);
            u32 v0 = r32[lane];
            u32 v1 = r32[lane + 64];
            u32 v2 = r32[lane + 128];
            u32 v3 = r32[tidx];
            p0 = fmaf(av, bf2f((u16)v0),         p0);
            p1 = fmaf(av, bf2f((u16)(v0 >> 16)), p1);
            p2 = fmaf(av, bf2f((u16)v1),         p2);
            p3 = fmaf(av, bf2f((u16)(v1 >> 16)), p3);
            p4 = fmaf(av, bf2f((u16)v2),         p4);
            p5 = fmaf(av, bf2f((u16)(v2 >> 16)), p5);
            p6 = fmaf(av, bf2f((u16)v3),         p6);
            p7 = fmaf(av, bf2f((u16)(v3 >> 16)), p7);
        }
        float* orow = out + (size_t)g * NEWS_DIM;
        *(float2*)(orow +       2 * lane) = make_float2(p0, p1);
        *(float2*)(orow + 128 + 2 * lane) = make_float2(p2, p3);
        *(float2*)(orow + 256 + 2 * lane) = make_float2(p4, p5);
        if (lane < 32)
            *(float2*)(orow + 384 + 2 * lane) = make_float2(p6, p7);
    }
}

extern "C" void kernel_launch(void* const* d_in, const int* in_sizes, int n_in,
                              void* d_out, int out_size, void* d_ws, size_t ws_size,
                              hipStream_t stream) {
    const float* logv  = (const float*)d_in[0];  // (64,50,384) f32
    const int*   lmask = (const int*)d_in[1];    // (64,50) i32
    const float* newsv = (const float*)d_in[2];  // (64,64,384) f32
    const float* pos   = (const float*)d_in[3];  // (100,64) f32; row 0 == 0
    const float* W1    = (const float*)d_in[4];  // (256,896) f32
    const float* b1    = (const float*)d_in[5];  // (256,) f32
    const float* w2    = (const float*)d_in[6];  // (1,256) f32
    // b2 unused (softmax-invariant shift)

    float* out = (float*)d_out;                  // [user_log | nf], f32
    float* nf  = out + (size_t)B_ * NN_ * NEWS_DIM;

    // d_ws ~256 MiB. Byte offsets, 16B aligned:
    char* ws = (char*)d_ws;
    u16*   lf_bf = (u16*)(ws + 0);               // 3200x448 bf16  (2,867,200 B)
    u16*   Wbf   = (u16*)(ws + 2867200);         // 256x896 bf16   (458,752 B)
    u16*   nv_bf = (u16*)(ws + 3325952);         // 4096x384 bf16  (3,145,728 B)
    float* pn    = (float*)(ws + 6471680);       // 4096x256 f32   (4,194,304 B)
    float* plT   = (float*)(ws + 10665984);      // 64x256x50 f32  (3,276,800 B)

    void* args[] = {
        (void*)&W1, (void*)&newsv, (void*)&logv, (void*)&pos,
        (void*)&lmask, (void*)&w2, (void*)&b1,
        (void*)&Wbf, (void*)&nv_bf, (void*)&lf_bf,
        (void*)&nf, (void*)&pn, (void*)&plT, (void*)&out
    };
    hipLaunchCooperativeKernel((const void*)fused_k, dim3(1024), dim3(256),
                               args, 0, stream);
}

// Round 7
// 138.046 us; speedup vs baseline: 2.5679x; 2.5679x over previous
//
#include <hip/hip_runtime.h>
#include <math.h>

typedef unsigned short u16;
typedef unsigned int   u32;

#define B_       64
#define NN_      64
#define HL_      50
#define IN_DIM   384
#define POS_DIM  64
#define ATT_DIM  256
#define NEWS_DIM 448   // IN_DIM + POS_DIM

typedef __attribute__((ext_vector_type(8))) short short8;   // bf16x8 MFMA frag
typedef __attribute__((ext_vector_type(4))) float f32x4;    // MFMA acc

#if __has_builtin(__builtin_amdgcn_exp2f)
#define EXP2F(x) __builtin_amdgcn_exp2f(x)
#else
#define EXP2F(x) exp2f(x)
#endif
#if __has_builtin(__builtin_amdgcn_rcpf)
#define RCPF(x) __builtin_amdgcn_rcpf(x)
#else
#define RCPF(x) (1.0f/(x))
#endif

__device__ __forceinline__ u16 f2bf(float f) {
    union { float f; u32 i; } v; v.f = f;
    u32 r = v.i + 0x7fffu + ((v.i >> 16) & 1u);   // RNE
    return (u16)(r >> 16);
}
__device__ __forceinline__ float bf2f(u16 u) {
    union { u32 i; float f; } v; v.i = ((u32)u) << 16; return v.f;
}
__device__ __forceinline__ uint2 pack4(float4 v) {
    return make_uint2((u32)f2bf(v.x) | ((u32)f2bf(v.y) << 16),
                      (u32)f2bf(v.z) | ((u32)f2bf(v.w) << 16));
}
// tanh(x) = 1 - 2/(1+2^(x*2*log2e)); v_exp+v_rcp saturate correctly at +-inf.
__device__ __forceinline__ float fast_tanh(float x) {
    float e = EXP2F(x * 2.88539008f);
    return 1.0f - 2.0f * RCPF(1.0f + e);
}

// ---------------- K0: bf16-convert W1/newsv/lf into ws; nf (f32) -> d_out.
// BYTE-IDENTICAL to R4 (XCD-aligned segments).
__global__ __launch_bounds__(256) void prep_k(
    const float* __restrict__ W1, const float* __restrict__ newsv,
    const float* __restrict__ logv, const float* __restrict__ pos,
    u16* __restrict__ Wbf, u16* __restrict__ nv_bf, u16* __restrict__ lf_bf,
    float* __restrict__ nf)
{
    u32 bid = blockIdx.x, tid = threadIdx.x;
    if (bid < 2936u) {
        u32 x = bid & 7u, j = bid >> 3;
        if (j < 192u) {            // newsv rows [512x, 512x+512) -> nv_bf + nf
            u32 idx = j * 256u + tid;              // < 49152
            u32 r = 512u * x + idx / 96u, d4 = idx % 96u;
            float4 v = *(const float4*)(newsv + (size_t)r * IN_DIM + d4 * 4u);
            *(uint2*)(nv_bf + (size_t)r * IN_DIM + d4 * 4u) = pack4(v);
            *(float4*)(nf + (size_t)r * NEWS_DIM + d4 * 4u) = v;
        } else if (j < 342u) {     // logv rows [400x, 400x+400) -> lf_bf head
            u32 idx = (j - 192u) * 256u + tid;     // < 38400
            u32 r = 400u * x + idx / 96u, d4 = idx % 96u;
            float4 v = *(const float4*)(logv + (size_t)r * IN_DIM + d4 * 4u);
            *(uint2*)(lf_bf + (size_t)r * NEWS_DIM + d4 * 4u) = pack4(v);
        } else {                   // pos tail, lf rows [400x, 400x+400)
            u32 idx = (j - 342u) * 256u + tid;     // < 6400
            u32 r = 400u * x + idx / 16u, d4 = idx % 16u;
            u32 h = r % HL_;
            float4 v = *(const float4*)(pos + (size_t)(1u + h) * POS_DIM + d4 * 4u);
            *(uint2*)(lf_bf + (size_t)r * NEWS_DIM + IN_DIM + d4 * 4u) = pack4(v);
        }
        return;
    }
    bid -= 2936u;
    if (bid < 224u) {              // W1 -> Wbf (read-shared; placement moot)
        u32 i = bid * 256u + tid;
        float4 v = *(const float4*)(W1 + (size_t)i * 4u);
        *(uint2*)(Wbf + (size_t)i * 4u) = pack4(v);
        return;
    }
    bid -= 224u;
    {                              // nf zero tail (no downstream reader)
        u32 i = bid * 256u + tid;  // < 65536
        u32 r = i / 16u, d4 = i % 16u;
        *(float4*)(nf + (size_t)r * NEWS_DIM + IN_DIM + d4 * 4u) =
            make_float4(0.f, 0.f, 0.f, 0.f);
    }
}

// ---------------- K1: fused NT GEMMs, 16x64-per-wave tiles (R3-proven).
// R17 change: pl stored in NATURAL layout pl2[(b*50+h)*256 + a] (was
// transposed [b][a][h]). This lets attn phase-1 read per-lane rows with
// float4 loads (4x fewer VMEM instructions). Store is same-coalesced as
// the pn branch and drops a div/mod. Everything else identical to R4.
__global__ __launch_bounds__(64) void gemm_k(
    const u16* __restrict__ nv_bf, const u16* __restrict__ lf_bf,
    const u16* __restrict__ Wbf, const float* __restrict__ b1,
    float* __restrict__ pn, float* __restrict__ pl2)
{
    int bid = blockIdx.x;          // 1824 = 8*228
    int lane = threadIdx.x;
    int m = lane & 15, q = lane >> 4;
    int x = bid & 7, j = bid >> 3; // j in [0,228)
    bool is_pn = j < 128;
    int r0, c0, lda, koff, klen;
    const u16* A;
    if (is_pn) {                   // 16 tiles per b: 4 row-bands x 4 col-tiles
        int b = x * 8 + (j >> 4);
        r0 = b * 64 + ((j >> 2) & 3) * 16;
        c0 = (j & 3) * 64;
        A = nv_bf; lda = IN_DIM;   koff = 0;        klen = IN_DIM;
    } else {                       // 100 tiles: 25 row-bands x 4 col-tiles
        int j2 = j - 128;
        r0 = 400 * x + (j2 >> 2) * 16;
        c0 = (j2 & 3) * 64;
        A = lf_bf; lda = NEWS_DIM; koff = NEWS_DIM; klen = NEWS_DIM;
    }

    f32x4 acc[4];
#pragma unroll
    for (int b = 0; b < 4; b++) acc[b] = (f32x4){0.f, 0.f, 0.f, 0.f};

    const u16* Ap = A + (size_t)(r0 + m) * lda + q * 8;
    const u16* Wp = Wbf + (size_t)(c0 + m) * (2 * NEWS_DIM) + koff + q * 8;

    for (int k = 0; k < klen; k += 32) {
        short8 af, wf[4];
        af = *(const short8*)(Ap + k);
#pragma unroll
        for (int ct = 0; ct < 4; ct++) wf[ct] = *(const short8*)(Wp + ct * 16 * (2 * NEWS_DIM) + k);
#pragma unroll
        for (int ct = 0; ct < 4; ct++)
            acc[ct] = __builtin_amdgcn_mfma_f32_16x16x32_bf16(af, wf[ct], acc[ct], 0, 0, 0);
    }
    // C/D layout: col = lane&15, row = (lane>>4)*4 + i  [m89]
#pragma unroll
    for (int ct = 0; ct < 4; ct++)
#pragma unroll
        for (int i = 0; i < 4; i++) {
            int gr = r0 + q * 4 + i;
            int gc = c0 + ct * 16 + m;
            float v = acc[ct][i];
            if (is_pn) {
                pn[(size_t)gr * ATT_DIM + gc] = v + b1[gc];
            } else {
                pl2[(size_t)gr * ATT_DIM + gc] = v;   // natural layout
            }
        }
}

// ---------------- K2: FUSED logits -> masked softmax -> out = attn x lf.
// R17: latency attack via VMEM instruction count (occupancy twice-null).
// Per-wave loads: 456 -> ~164.
//  phase 1: pl natural layout -> lane=h streams its row as 64 float4
//           loads (was 256 scalar); L1 absorbs sector amplification
//           (each lane's next 3 loads hit the fetched 64B line).
//  phase 2: lf as uint2 (4 bf16/load) -> 100 loads (was 200); 2 float4
//           stores. Per-output arithmetic order unchanged (bit-identical).
__global__ __launch_bounds__(256) void attn_out_k(
    const float* __restrict__ pn, const float* __restrict__ pl2,
    const float* __restrict__ w2, const int* __restrict__ lmask,
    const u16* __restrict__ lf_bf, float* __restrict__ out)
{
    __shared__ float at_s[4][64];              // per-wave attn slices, 1 KB
    int lane = threadIdx.x & 63;
    int wid = __builtin_amdgcn_readfirstlane((int)(threadIdx.x >> 6));
    // XCD-clustered work mapping (bijective over 1024 blocks):
    int x     = blockIdx.x & 7;                // assumed XCD id
    int local = blockIdx.x >> 3;               // [0,128) within XCD
    int b     = x * 8 + (local >> 4);          // 8 b's per XCD
    int sub   = local & 15;                    // 16 blocks per b
    int g     = b * 64 + sub * 4 + wid;        // uniform (SGPR)
    int n_hl  = (lane < HL_) ? lane : (HL_ - 1);   // clamp reads
    const float4* w2v = (const float4*)w2;                      // uniform
    const float4* prv = (const float4*)(pn + (size_t)g * ATT_DIM);   // uniform
    const float4* plv = (const float4*)(pl2 + ((size_t)b * HL_ + n_hl) * ATT_DIM);

    float a0 = 0.f, a1 = 0.f, a2 = 0.f, a3 = 0.f;
#pragma unroll 8
    for (int a4 = 0; a4 < ATT_DIM / 4; a4++) {
        float4 w4 = w2v[a4];                   // uniform -> s_load
        float4 p  = prv[a4];                   // uniform -> s_load
        float4 l  = plv[a4];                   // per-lane float4
        a0 = __builtin_fmaf(fast_tanh(p.x + l.x), w4.x, a0);
        a1 = __builtin_fmaf(fast_tanh(p.y + l.y), w4.y, a1);
        a2 = __builtin_fmaf(fast_tanh(p.z + l.z), w4.z, a2);
        a3 = __builtin_fmaf(fast_tanh(p.w + l.w), w4.w, a3);
    }
    float acc = (a0 + a1) + (a2 + a3);
    int mv = (lane < HL_) ? lmask[b * HL_ + lane] : 0;
    float logit = mv ? acc : -1e9f;            // b2 dropped: softmax-invariant
    float mx = logit;
#pragma unroll
    for (int o = 32; o > 0; o >>= 1) mx = fmaxf(mx, __shfl_xor(mx, o));
    float e = EXP2F((logit - mx) * 1.44269504f);   // masked lanes -> 0
    float s = e;
#pragma unroll
    for (int o = 32; o > 0; o >>= 1) s += __shfl_xor(s, o);
    at_s[wid][lane] = e * RCPF(s);
    // no barrier: same wave writes & reads its own slice (lgkmcnt enforced)

    // phase 2: out[b,n][d] via uint2 lf loads (4 bf16 each). Row = 112
    // uint2; lane covers k0 = lane (d=[0,256)) and k1 = 64 + l48
    // (d=[256,448), lanes 48-63 duplicate and don't store).
    const uint2* lfb2 = (const uint2*)(lf_bf + (size_t)b * HL_ * NEWS_DIM);
    int l48 = (lane < 48) ? lane : (lane - 48);
    int k1  = 64 + l48;
    float q0 = 0.f, q1 = 0.f, q2 = 0.f, q3 = 0.f;
    float r0 = 0.f, r1 = 0.f, r2 = 0.f, r3 = 0.f;
    for (int h = 0; h < HL_; h++) {
        float av = at_s[wid][h];               // LDS broadcast
        const uint2* row = lfb2 + h * (NEWS_DIM / 4);
        uint2 v0 = row[lane];
        uint2 v1 = row[k1];
        q0 = fmaf(av, bf2f((u16)v0.x),         q0);
        q1 = fmaf(av, bf2f((u16)(v0.x >> 16)), q1);
        q2 = fmaf(av, bf2f((u16)v0.y),         q2);
        q3 = fmaf(av, bf2f((u16)(v0.y >> 16)), q3);
        r0 = fmaf(av, bf2f((u16)v1.x),         r0);
        r1 = fmaf(av, bf2f((u16)(v1.x >> 16)), r1);
        r2 = fmaf(av, bf2f((u16)v1.y),         r2);
        r3 = fmaf(av, bf2f((u16)(v1.y >> 16)), r3);
    }
    float* orow = out + (size_t)g * NEWS_DIM;
    *(float4*)(orow + 4 * lane) = make_float4(q0, q1, q2, q3);
    if (lane < 48)
        *(float4*)(orow + 4 * k1) = make_float4(r0, r1, r2, r3);
}

extern "C" void kernel_launch(void* const* d_in, const int* in_sizes, int n_in,
                              void* d_out, int out_size, void* d_ws, size_t ws_size,
                              hipStream_t stream) {
    const float* logv  = (const float*)d_in[0];  // (64,50,384) f32
    const int*   lmask = (const int*)d_in[1];    // (64,50) i32
    const float* newsv = (const float*)d_in[2];  // (64,64,384) f32
    const float* pos   = (const float*)d_in[3];  // (100,64) f32; row 0 == 0
    const float* W1    = (const float*)d_in[4];  // (256,896) f32
    const float* b1    = (const float*)d_in[5];  // (256,) f32
    const float* w2    = (const float*)d_in[6];  // (1,256) f32
    // b2 unused (softmax-invariant shift)

    float* out = (float*)d_out;                  // [user_log | nf], f32
    float* nf  = out + (size_t)B_ * NN_ * NEWS_DIM;

    // d_ws ~256 MiB. Byte offsets, 16B aligned:
    char* ws = (char*)d_ws;
    u16*   lf_bf = (u16*)(ws + 0);               // 3200x448 bf16  (2,867,200 B)
    u16*   Wbf   = (u16*)(ws + 2867200);         // 256x896 bf16   (458,752 B)
    u16*   nv_bf = (u16*)(ws + 3325952);         // 4096x384 bf16  (3,145,728 B)
    float* pn    = (float*)(ws + 6471680);       // 4096x256 f32   (4,194,304 B)
    float* pl2   = (float*)(ws + 10665984);      // 3200x256 f32   (3,276,800 B)

    prep_k    <<<3416, 256, 0, stream>>>(W1, newsv, logv, pos,
                                         Wbf, nv_bf, lf_bf, nf);
    gemm_k    <<<1824, 64, 0, stream>>>(nv_bf, lf_bf, Wbf, b1, pn, pl2);
    attn_out_k<<<1024, 256, 0, stream>>>(pn, pl2, w2, lmask, lf_bf, out);
}

// Round 8
// 127.906 us; speedup vs baseline: 2.7715x; 1.0793x over previous
//
#include <hip/hip_runtime.h>
#include <math.h>

typedef unsigned short u16;
typedef unsigned int   u32;

#define B_       64
#define NN_      64
#define HL_      50
#define IN_DIM   384
#define POS_DIM  64
#define ATT_DIM  256
#define NEWS_DIM 448   // IN_DIM + POS_DIM

typedef __attribute__((ext_vector_type(8))) short short8;   // bf16x8 MFMA frag
typedef __attribute__((ext_vector_type(4))) float f32x4;    // MFMA acc

#if __has_builtin(__builtin_amdgcn_exp2f)
#define EXP2F(x) __builtin_amdgcn_exp2f(x)
#else
#define EXP2F(x) exp2f(x)
#endif
#if __has_builtin(__builtin_amdgcn_rcpf)
#define RCPF(x) __builtin_amdgcn_rcpf(x)
#else
#define RCPF(x) (1.0f/(x))
#endif

__device__ __forceinline__ u16 f2bf(float f) {
    union { float f; u32 i; } v; v.f = f;
    u32 r = v.i + 0x7fffu + ((v.i >> 16) & 1u);   // RNE
    return (u16)(r >> 16);
}
__device__ __forceinline__ float bf2f(u16 u) {
    union { u32 i; float f; } v; v.i = ((u32)u) << 16; return v.f;
}
__device__ __forceinline__ uint2 pack4(float4 v) {
    return make_uint2((u32)f2bf(v.x) | ((u32)f2bf(v.y) << 16),
                      (u32)f2bf(v.z) | ((u32)f2bf(v.w) << 16));
}
// tanh(x) = 1 - 2/(1+2^(x*2*log2e)); v_exp+v_rcp saturate correctly at +-inf.
__device__ __forceinline__ float fast_tanh(float x) {
    float e = EXP2F(x * 2.88539008f);
    return 1.0f - 2.0f * RCPF(1.0f + e);
}

// ---------------- K0: bf16-convert W1/newsv/lf into ws; nf (f32) -> d_out.
// BYTE-IDENTICAL to R4 (XCD-aligned segments).
__global__ __launch_bounds__(256) void prep_k(
    const float* __restrict__ W1, const float* __restrict__ newsv,
    const float* __restrict__ logv, const float* __restrict__ pos,
    u16* __restrict__ Wbf, u16* __restrict__ nv_bf, u16* __restrict__ lf_bf,
    float* __restrict__ nf)
{
    u32 bid = blockIdx.x, tid = threadIdx.x;
    if (bid < 2936u) {
        u32 x = bid & 7u, j = bid >> 3;
        if (j < 192u) {            // newsv rows [512x, 512x+512) -> nv_bf + nf
            u32 idx = j * 256u + tid;              // < 49152
            u32 r = 512u * x + idx / 96u, d4 = idx % 96u;
            float4 v = *(const float4*)(newsv + (size_t)r * IN_DIM + d4 * 4u);
            *(uint2*)(nv_bf + (size_t)r * IN_DIM + d4 * 4u) = pack4(v);
            *(float4*)(nf + (size_t)r * NEWS_DIM + d4 * 4u) = v;
        } else if (j < 342u) {     // logv rows [400x, 400x+400) -> lf_bf head
            u32 idx = (j - 192u) * 256u + tid;     // < 38400
            u32 r = 400u * x + idx / 96u, d4 = idx % 96u;
            float4 v = *(const float4*)(logv + (size_t)r * IN_DIM + d4 * 4u);
            *(uint2*)(lf_bf + (size_t)r * NEWS_DIM + d4 * 4u) = pack4(v);
        } else {                   // pos tail, lf rows [400x, 400x+400)
            u32 idx = (j - 342u) * 256u + tid;     // < 6400
            u32 r = 400u * x + idx / 16u, d4 = idx % 16u;
            u32 h = r % HL_;
            float4 v = *(const float4*)(pos + (size_t)(1u + h) * POS_DIM + d4 * 4u);
            *(uint2*)(lf_bf + (size_t)r * NEWS_DIM + IN_DIM + d4 * 4u) = pack4(v);
        }
        return;
    }
    bid -= 2936u;
    if (bid < 224u) {              // W1 -> Wbf (read-shared; placement moot)
        u32 i = bid * 256u + tid;
        float4 v = *(const float4*)(W1 + (size_t)i * 4u);
        *(uint2*)(Wbf + (size_t)i * 4u) = pack4(v);
        return;
    }
    bid -= 224u;
    {                              // nf zero tail (no downstream reader)
        u32 i = bid * 256u + tid;  // < 65536
        u32 r = i / 16u, d4 = i % 16u;
        *(float4*)(nf + (size_t)r * NEWS_DIM + IN_DIM + d4 * 4u) =
            make_float4(0.f, 0.f, 0.f, 0.f);
    }
}

// ---------------- K1: fused NT GEMMs, 16x64-per-wave tiles.
// BYTE-IDENTICAL to R4 (transposed plT store restored -- R7 proved the
// natural layout makes attn's read transaction-bound: 64 lines/inst).
__global__ __launch_bounds__(64) void gemm_k(
    const u16* __restrict__ nv_bf, const u16* __restrict__ lf_bf,
    const u16* __restrict__ Wbf, const float* __restrict__ b1,
    float* __restrict__ pn, float* __restrict__ plT)
{
    int bid = blockIdx.x;          // 1824 = 8*228
    int lane = threadIdx.x;
    int m = lane & 15, q = lane >> 4;
    int x = bid & 7, j = bid >> 3; // j in [0,228)
    bool is_pn = j < 128;
    int r0, c0, lda, koff, klen;
    const u16* A;
    if (is_pn) {                   // 16 tiles per b: 4 row-bands x 4 col-tiles
        int b = x * 8 + (j >> 4);
        r0 = b * 64 + ((j >> 2) & 3) * 16;
        c0 = (j & 3) * 64;
        A = nv_bf; lda = IN_DIM;   koff = 0;        klen = IN_DIM;
    } else {                       // 100 tiles: 25 row-bands x 4 col-tiles
        int j2 = j - 128;
        r0 = 400 * x + (j2 >> 2) * 16;
        c0 = (j2 & 3) * 64;
        A = lf_bf; lda = NEWS_DIM; koff = NEWS_DIM; klen = NEWS_DIM;
    }

    f32x4 acc[4];
#pragma unroll
    for (int b = 0; b < 4; b++) acc[b] = (f32x4){0.f, 0.f, 0.f, 0.f};

    const u16* Ap = A + (size_t)(r0 + m) * lda + q * 8;
    const u16* Wp = Wbf + (size_t)(c0 + m) * (2 * NEWS_DIM) + koff + q * 8;

    for (int k = 0; k < klen; k += 32) {
        short8 af, wf[4];
        af = *(const short8*)(Ap + k);
#pragma unroll
        for (int ct = 0; ct < 4; ct++) wf[ct] = *(const short8*)(Wp + ct * 16 * (2 * NEWS_DIM) + k);
#pragma unroll
        for (int ct = 0; ct < 4; ct++)
            acc[ct] = __builtin_amdgcn_mfma_f32_16x16x32_bf16(af, wf[ct], acc[ct], 0, 0, 0);
    }
    // C/D layout: col = lane&15, row = (lane>>4)*4 + i  [m89]
#pragma unroll
    for (int ct = 0; ct < 4; ct++)
#pragma unroll
        for (int i = 0; i < 4; i++) {
            int gr = r0 + q * 4 + i;
            int gc = c0 + ct * 16 + m;
            float v = acc[ct][i];
            if (is_pn) {
                pn[(size_t)gr * ATT_DIM + gc] = v + b1[gc];
            } else {
                int bb = gr / HL_, hh = gr - bb * HL_;
                plT[(size_t)(bb * ATT_DIM + gc) * HL_ + hh] = v;
            }
        }
}

// ---------------- K2: FUSED logits -> masked softmax -> out = attn x lf.
// R18: identical to R4 except phase 1 runs EIGHT independent accumulator
// chains (was 4). R7's profile (VALUBusy 39%, FETCH 7MB, occ 31%) showed
// attn is dependency-latency-bound: each chain was 64 serial ~20cy tanh
// links (load->add->exp->fma->rcp->fma). 8 chains halve the chain length
// and double loads in flight. Transposed plT reads kept (R7 proved
// coalescing across lanes >> per-lane width). Sum reassoc ~1e-6, ok.
__global__ __launch_bounds__(256) void attn_out_k(
    const float* __restrict__ pn, const float* __restrict__ plT,
    const float* __restrict__ w2, const int* __restrict__ lmask,
    const u16* __restrict__ lf_bf, float* __restrict__ out)
{
    __shared__ float at_s[4][64];              // per-wave attn slices, 1 KB
    int lane = threadIdx.x & 63;
    int wid = __builtin_amdgcn_readfirstlane((int)(threadIdx.x >> 6));
    // XCD-clustered work mapping (bijective over 1024 blocks):
    int x     = blockIdx.x & 7;                // assumed XCD id
    int local = blockIdx.x >> 3;               // [0,128) within XCD
    int b     = x * 8 + (local >> 4);          // 8 b's per XCD
    int sub   = local & 15;                    // 16 blocks per b
    int g     = b * 64 + sub * 4 + wid;        // uniform (SGPR)
    int n_hl  = (lane < HL_) ? lane : (HL_ - 1);   // clamp reads
    const float* pr = pn + (size_t)g * ATT_DIM;    // uniform -> s_load
    const float* pl = plT + (size_t)b * ATT_DIM * HL_ + n_hl;

    float a0 = 0.f, a1 = 0.f, a2 = 0.f, a3 = 0.f,
          a4 = 0.f, a5 = 0.f, a6 = 0.f, a7 = 0.f;
#pragma unroll 4
    for (int a = 0; a < ATT_DIM; a += 8) {
        float4 wA = *(const float4*)(w2 + a);      // uniform -> s_load
        float4 wB = *(const float4*)(w2 + a + 4);
        float4 pA = *(const float4*)(pr + a);      // uniform -> s_load
        float4 pB = *(const float4*)(pr + a + 4);
        float l0 = pl[(a + 0) * HL_];
        float l1 = pl[(a + 1) * HL_];
        float l2 = pl[(a + 2) * HL_];
        float l3 = pl[(a + 3) * HL_];
        float l4 = pl[(a + 4) * HL_];
        float l5 = pl[(a + 5) * HL_];
        float l6 = pl[(a + 6) * HL_];
        float l7 = pl[(a + 7) * HL_];
        a0 = __builtin_fmaf(fast_tanh(pA.x + l0), wA.x, a0);
        a1 = __builtin_fmaf(fast_tanh(pA.y + l1), wA.y, a1);
        a2 = __builtin_fmaf(fast_tanh(pA.z + l2), wA.z, a2);
        a3 = __builtin_fmaf(fast_tanh(pA.w + l3), wA.w, a3);
        a4 = __builtin_fmaf(fast_tanh(pB.x + l4), wB.x, a4);
        a5 = __builtin_fmaf(fast_tanh(pB.y + l5), wB.y, a5);
        a6 = __builtin_fmaf(fast_tanh(pB.z + l6), wB.z, a6);
        a7 = __builtin_fmaf(fast_tanh(pB.w + l7), wB.w, a7);
    }
    float acc = ((a0 + a1) + (a2 + a3)) + ((a4 + a5) + (a6 + a7));
    int mv = (lane < HL_) ? lmask[b * HL_ + lane] : 0;
    float logit = mv ? acc : -1e9f;            // b2 dropped: softmax-invariant
    float mx = logit;
#pragma unroll
    for (int o = 32; o > 0; o >>= 1) mx = fmaxf(mx, __shfl_xor(mx, o));
    float e = EXP2F((logit - mx) * 1.44269504f);   // masked lanes -> 0
    float s = e;
#pragma unroll
    for (int o = 32; o > 0; o >>= 1) s += __shfl_xor(s, o);
    at_s[wid][lane] = e * RCPF(s);
    // no barrier: same wave writes & reads its own slice (lgkmcnt enforced)

    // phase 2: out[b,n][d]. Packed u32 bf16 loads (R4-proven): lane covers
    // d-pairs {2l,2l+1}+128j (j<3) + tail 384+2*(l&31) (lanes<32 store).
    const u32* lfb32 = (const u32*)(lf_bf + (size_t)b * HL_ * NEWS_DIM);
    int tidx = 192 + (lane & 31);              // safe duplicate for lane>=32
    float p0 = 0.f, p1 = 0.f, p2 = 0.f, p3 = 0.f,
          p4 = 0.f, p5 = 0.f, p6 = 0.f, p7 = 0.f;
    for (int h = 0; h < HL_; h++) {
        float av = at_s[wid][h];               // LDS broadcast
        const u32* r32 = lfb32 + h * (NEWS_DIM / 2);
        u32 v0 = r32[lane];
        u32 v1 = r32[lane + 64];
        u32 v2 = r32[lane + 128];
        u32 v3 = r32[tidx];
        p0 = fmaf(av, bf2f((u16)v0),         p0);
        p1 = fmaf(av, bf2f((u16)(v0 >> 16)), p1);
        p2 = fmaf(av, bf2f((u16)v1),         p2);
        p3 = fmaf(av, bf2f((u16)(v1 >> 16)), p3);
        p4 = fmaf(av, bf2f((u16)v2),         p4);
        p5 = fmaf(av, bf2f((u16)(v2 >> 16)), p5);
        p6 = fmaf(av, bf2f((u16)v3),         p6);
        p7 = fmaf(av, bf2f((u16)(v3 >> 16)), p7);
    }
    float* orow = out + (size_t)g * NEWS_DIM;
    *(float2*)(orow +       2 * lane) = make_float2(p0, p1);
    *(float2*)(orow + 128 + 2 * lane) = make_float2(p2, p3);
    *(float2*)(orow + 256 + 2 * lane) = make_float2(p4, p5);
    if (lane < 32)
        *(float2*)(orow + 384 + 2 * lane) = make_float2(p6, p7);
}

extern "C" void kernel_launch(void* const* d_in, const int* in_sizes, int n_in,
                              void* d_out, int out_size, void* d_ws, size_t ws_size,
                              hipStream_t stream) {
    const float* logv  = (const float*)d_in[0];  // (64,50,384) f32
    const int*   lmask = (const int*)d_in[1];    // (64,50) i32
    const float* newsv = (const float*)d_in[2];  // (64,64,384) f32
    const float* pos   = (const float*)d_in[3];  // (100,64) f32; row 0 == 0
    const float* W1    = (const float*)d_in[4];  // (256,896) f32
    const float* b1    = (const float*)d_in[5];  // (256,) f32
    const float* w2    = (const float*)d_in[6];  // (1,256) f32
    // b2 unused (softmax-invariant shift)

    float* out = (float*)d_out;                  // [user_log | nf], f32
    float* nf  = out + (size_t)B_ * NN_ * NEWS_DIM;

    // d_ws ~256 MiB. Byte offsets, 16B aligned:
    char* ws = (char*)d_ws;
    u16*   lf_bf = (u16*)(ws + 0);               // 3200x448 bf16  (2,867,200 B)
    u16*   Wbf   = (u16*)(ws + 2867200);         // 256x896 bf16   (458,752 B)
    u16*   nv_bf = (u16*)(ws + 3325952);         // 4096x384 bf16  (3,145,728 B)
    float* pn    = (float*)(ws + 6471680);       // 4096x256 f32   (4,194,304 B)
    float* plT   = (float*)(ws + 10665984);      // 64x256x50 f32  (3,276,800 B)

    prep_k    <<<3416, 256, 0, stream>>>(W1, newsv, logv, pos,
                                         Wbf, nv_bf, lf_bf, nf);
    gemm_k    <<<1824, 64, 0, stream>>>(nv_bf, lf_bf, Wbf, b1, pn, plT);
    attn_out_k<<<1024, 256, 0, stream>>>(pn, plT, w2, lmask, lf_bf, out);
}

// Round 9
// 124.294 us; speedup vs baseline: 2.8520x; 1.0291x over previous
//
#include <hip/hip_runtime.h>
#include <math.h>

typedef unsigned short u16;
typedef unsigned int   u32;

#define B_       64
#define NN_      64
#define HL_      50
#define IN_DIM   384
#define POS_DIM  64
#define ATT_DIM  256
#define NEWS_DIM 448   // IN_DIM + POS_DIM

typedef __attribute__((ext_vector_type(8))) short short8;   // bf16x8 MFMA frag
typedef __attribute__((ext_vector_type(4))) float f32x4;    // MFMA acc

#if __has_builtin(__builtin_amdgcn_exp2f)
#define EXP2F(x) __builtin_amdgcn_exp2f(x)
#else
#define EXP2F(x) exp2f(x)
#endif
#if __has_builtin(__builtin_amdgcn_rcpf)
#define RCPF(x) __builtin_amdgcn_rcpf(x)
#else
#define RCPF(x) (1.0f/(x))
#endif

__device__ __forceinline__ u16 f2bf(float f) {
    union { float f; u32 i; } v; v.f = f;
    u32 r = v.i + 0x7fffu + ((v.i >> 16) & 1u);   // RNE
    return (u16)(r >> 16);
}
__device__ __forceinline__ float bf2f(u16 u) {
    union { u32 i; float f; } v; v.i = ((u32)u) << 16; return v.f;
}
__device__ __forceinline__ uint2 pack4(float4 v) {
    return make_uint2((u32)f2bf(v.x) | ((u32)f2bf(v.y) << 16),
                      (u32)f2bf(v.z) | ((u32)f2bf(v.w) << 16));
}
// tanh(x) = 1 - 2/(1+2^(x*2*log2e)); v_exp+v_rcp saturate correctly at +-inf.
__device__ __forceinline__ float fast_tanh(float x) {
    float e = EXP2F(x * 2.88539008f);
    return 1.0f - 2.0f * RCPF(1.0f + e);
}

// ---------------- K0: bf16-convert W1/newsv/lf into ws; nf (f32) -> d_out.
// BYTE-IDENTICAL to R4 (XCD-aligned segments).
__global__ __launch_bounds__(256) void prep_k(
    const float* __restrict__ W1, const float* __restrict__ newsv,
    const float* __restrict__ logv, const float* __restrict__ pos,
    u16* __restrict__ Wbf, u16* __restrict__ nv_bf, u16* __restrict__ lf_bf,
    float* __restrict__ nf)
{
    u32 bid = blockIdx.x, tid = threadIdx.x;
    if (bid < 2936u) {
        u32 x = bid & 7u, j = bid >> 3;
        if (j < 192u) {            // newsv rows [512x, 512x+512) -> nv_bf + nf
            u32 idx = j * 256u + tid;              // < 49152
            u32 r = 512u * x + idx / 96u, d4 = idx % 96u;
            float4 v = *(const float4*)(newsv + (size_t)r * IN_DIM + d4 * 4u);
            *(uint2*)(nv_bf + (size_t)r * IN_DIM + d4 * 4u) = pack4(v);
            *(float4*)(nf + (size_t)r * NEWS_DIM + d4 * 4u) = v;
        } else if (j < 342u) {     // logv rows [400x, 400x+400) -> lf_bf head
            u32 idx = (j - 192u) * 256u + tid;     // < 38400
            u32 r = 400u * x + idx / 96u, d4 = idx % 96u;
            float4 v = *(const float4*)(logv + (size_t)r * IN_DIM + d4 * 4u);
            *(uint2*)(lf_bf + (size_t)r * NEWS_DIM + d4 * 4u) = pack4(v);
        } else {                   // pos tail, lf rows [400x, 400x+400)
            u32 idx = (j - 342u) * 256u + tid;     // < 6400
            u32 r = 400u * x + idx / 16u, d4 = idx % 16u;
            u32 h = r % HL_;
            float4 v = *(const float4*)(pos + (size_t)(1u + h) * POS_DIM + d4 * 4u);
            *(uint2*)(lf_bf + (size_t)r * NEWS_DIM + IN_DIM + d4 * 4u) = pack4(v);
        }
        return;
    }
    bid -= 2936u;
    if (bid < 224u) {              // W1 -> Wbf (read-shared; placement moot)
        u32 i = bid * 256u + tid;
        float4 v = *(const float4*)(W1 + (size_t)i * 4u);
        *(uint2*)(Wbf + (size_t)i * 4u) = pack4(v);
        return;
    }
    bid -= 224u;
    {                              // nf zero tail (no downstream reader)
        u32 i = bid * 256u + tid;  // < 65536
        u32 r = i / 16u, d4 = i % 16u;
        *(float4*)(nf + (size_t)r * NEWS_DIM + IN_DIM + d4 * 4u) =
            make_float4(0.f, 0.f, 0.f, 0.f);
    }
}

// ---------------- K1: fused NT GEMMs, 16x64-per-wave tiles.
// BYTE-IDENTICAL to R4.
__global__ __launch_bounds__(64) void gemm_k(
    const u16* __restrict__ nv_bf, const u16* __restrict__ lf_bf,
    const u16* __restrict__ Wbf, const float* __restrict__ b1,
    float* __restrict__ pn, float* __restrict__ plT)
{
    int bid = blockIdx.x;          // 1824 = 8*228
    int lane = threadIdx.x;
    int m = lane & 15, q = lane >> 4;
    int x = bid & 7, j = bid >> 3; // j in [0,228)
    bool is_pn = j < 128;
    int r0, c0, lda, koff, klen;
    const u16* A;
    if (is_pn) {                   // 16 tiles per b: 4 row-bands x 4 col-tiles
        int b = x * 8 + (j >> 4);
        r0 = b * 64 + ((j >> 2) & 3) * 16;
        c0 = (j & 3) * 64;
        A = nv_bf; lda = IN_DIM;   koff = 0;        klen = IN_DIM;
    } else {                       // 100 tiles: 25 row-bands x 4 col-tiles
        int j2 = j - 128;
        r0 = 400 * x + (j2 >> 2) * 16;
        c0 = (j2 & 3) * 64;
        A = lf_bf; lda = NEWS_DIM; koff = NEWS_DIM; klen = NEWS_DIM;
    }

    f32x4 acc[4];
#pragma unroll
    for (int b = 0; b < 4; b++) acc[b] = (f32x4){0.f, 0.f, 0.f, 0.f};

    const u16* Ap = A + (size_t)(r0 + m) * lda + q * 8;
    const u16* Wp = Wbf + (size_t)(c0 + m) * (2 * NEWS_DIM) + koff + q * 8;

    for (int k = 0; k < klen; k += 32) {
        short8 af, wf[4];
        af = *(const short8*)(Ap + k);
#pragma unroll
        for (int ct = 0; ct < 4; ct++) wf[ct] = *(const short8*)(Wp + ct * 16 * (2 * NEWS_DIM) + k);
#pragma unroll
        for (int ct = 0; ct < 4; ct++)
            acc[ct] = __builtin_amdgcn_mfma_f32_16x16x32_bf16(af, wf[ct], acc[ct], 0, 0, 0);
    }
    // C/D layout: col = lane&15, row = (lane>>4)*4 + i  [m89]
#pragma unroll
    for (int ct = 0; ct < 4; ct++)
#pragma unroll
        for (int i = 0; i < 4; i++) {
            int gr = r0 + q * 4 + i;
            int gc = c0 + ct * 16 + m;
            float v = acc[ct][i];
            if (is_pn) {
                pn[(size_t)gr * ATT_DIM + gc] = v + b1[gc];
            } else {
                int bb = gr / HL_, hh = gr - bb * HL_;
                plT[(size_t)(bb * ATT_DIM + gc) * HL_ + hh] = v;
            }
        }
}

// ---------------- K2: FUSED logits -> masked softmax -> out = attn x lf.
// R19: 4x DATA REUSE PER LOAD. Block owns (b, n-quad). Phase 1: 4 waves
// split the a-range (64 each); each pl load feeds tanh+fma for 4 n's
// (loads/wave 256->64, tanh unchanged -- it's irreducible). Partials
// combine via 4KB LDS (R5-proven ~free); wave w softmaxes n=w. Phase 2:
// 4 waves split d-range; each lf u32 load feeds 4 n-accs (200->50).
// Same wave count (1024x4), same VALU, 4x fewer VMEM instr + 4x less L2
// request traffic. Occupancy/ILP/XCD levers all measured null; reuse is
// the untried axis. Phase-2 per-output h-order unchanged (bit-identical).
__global__ __launch_bounds__(256) void attn_out_k(
    const float* __restrict__ pn, const float* __restrict__ plT,
    const float* __restrict__ w2, const int* __restrict__ lmask,
    const u16* __restrict__ lf_bf, float* __restrict__ out)
{
    __shared__ float part[4][4][64];           // [a-quarter][n][h]  4KB
    __shared__ float at4[64][4];               // [h][n] attn weights 1KB
    int lane = threadIdx.x & 63;
    int wid = __builtin_amdgcn_readfirstlane((int)(threadIdx.x >> 6)); // 0..3
    // XCD-clustered map: XCD x owns b in [8x,8x+8); 16 n-quads per b.
    int x     = blockIdx.x & 7;
    int local = blockIdx.x >> 3;               // [0,128)
    int b     = x * 8 + (local >> 4);
    int n0    = (local & 15) * 4;              // n-quad base
    int g0    = b * 64 + n0;                   // first of 4 pn/out rows
    int n_hl  = (lane < HL_) ? lane : (HL_ - 1);

    // ---- phase 1: a-range [64*wid, 64*wid+64), 4 n's per pl load ----
    int a0 = wid * 64;
    const float* pl  = plT + ((size_t)b * ATT_DIM + a0) * HL_ + n_hl;
    const float* pr0 = pn + (size_t)(g0 + 0) * ATT_DIM + a0;  // uniform
    const float* pr1 = pn + (size_t)(g0 + 1) * ATT_DIM + a0;
    const float* pr2 = pn + (size_t)(g0 + 2) * ATT_DIM + a0;
    const float* pr3 = pn + (size_t)(g0 + 3) * ATT_DIM + a0;
    const float* w2o = w2 + a0;

    float c0 = 0.f, c1 = 0.f, c2 = 0.f, c3 = 0.f;   // chain A per n
    float d0 = 0.f, d1 = 0.f, d2 = 0.f, d3 = 0.f;   // chain B per n
#pragma unroll 4
    for (int a = 0; a < 64; a += 4) {
        float4 w4 = *(const float4*)(w2o + a);      // uniform -> s_load
        float4 pA = *(const float4*)(pr0 + a);      // uniform -> s_load
        float4 pB = *(const float4*)(pr1 + a);
        float4 pC = *(const float4*)(pr2 + a);
        float4 pD = *(const float4*)(pr3 + a);
        float l0 = pl[(a + 0) * HL_];
        float l1 = pl[(a + 1) * HL_];
        float l2 = pl[(a + 2) * HL_];
        float l3 = pl[(a + 3) * HL_];
        c0 = __builtin_fmaf(fast_tanh(pA.x + l0), w4.x, c0);
        d0 = __builtin_fmaf(fast_tanh(pA.y + l1), w4.y, d0);
        c0 = __builtin_fmaf(fast_tanh(pA.z + l2), w4.z, c0);
        d0 = __builtin_fmaf(fast_tanh(pA.w + l3), w4.w, d0);
        c1 = __builtin_fmaf(fast_tanh(pB.x + l0), w4.x, c1);
        d1 = __builtin_fmaf(fast_tanh(pB.y + l1), w4.y, d1);
        c1 = __builtin_fmaf(fast_tanh(pB.z + l2), w4.z, c1);
        d1 = __builtin_fmaf(fast_tanh(pB.w + l3), w4.w, d1);
        c2 = __builtin_fmaf(fast_tanh(pC.x + l0), w4.x, c2);
        d2 = __builtin_fmaf(fast_tanh(pC.y + l1), w4.y, d2);
        c2 = __builtin_fmaf(fast_tanh(pC.z + l2), w4.z, c2);
        d2 = __builtin_fmaf(fast_tanh(pC.w + l3), w4.w, d2);
        c3 = __builtin_fmaf(fast_tanh(pD.x + l0), w4.x, c3);
        d3 = __builtin_fmaf(fast_tanh(pD.y + l1), w4.y, d3);
        c3 = __builtin_fmaf(fast_tanh(pD.z + l2), w4.z, c3);
        d3 = __builtin_fmaf(fast_tanh(pD.w + l3), w4.w, d3);
    }
    part[wid][0][lane] = c0 + d0;
    part[wid][1][lane] = c1 + d1;
    part[wid][2][lane] = c2 + d2;
    part[wid][3][lane] = c3 + d3;
    __syncthreads();

    // ---- softmax: wave wid handles n = wid ----
    float acc = (part[0][wid][lane] + part[1][wid][lane])
              + (part[2][wid][lane] + part[3][wid][lane]);
    int mv = (lane < HL_) ? lmask[b * HL_ + lane] : 0;
    float logit = mv ? acc : -1e9f;            // b2 dropped: softmax-invariant
    float mx = logit;
#pragma unroll
    for (int o = 32; o > 0; o >>= 1) mx = fmaxf(mx, __shfl_xor(mx, o));
    float e = EXP2F((logit - mx) * 1.44269504f);   // masked lanes -> 0
    float s = e;
#pragma unroll
    for (int o = 32; o > 0; o >>= 1) s += __shfl_xor(s, o);
    at4[lane][wid] = e * RCPF(s);
    __syncthreads();

    // ---- phase 2: wave wid covers u32 range [56*wid, 56*wid+56), 4 n's ----
    // lane>=56 duplicates (no store). One ds_read_b128 broadcast per h.
    int l56 = (lane < 56) ? lane : 55;
    int k   = wid * 56 + l56;                  // u32 index in row of 224
    const u32* lfb32 = (const u32*)(lf_bf + (size_t)b * HL_ * NEWS_DIM);
    float q00 = 0.f, q01 = 0.f, q10 = 0.f, q11 = 0.f;
    float q20 = 0.f, q21 = 0.f, q30 = 0.f, q31 = 0.f;
    for (int h = 0; h < HL_; h++) {
        float4 av = *(const float4*)at4[h];    // LDS broadcast, 4 attn vals
        u32 v = lfb32[h * (NEWS_DIM / 2) + k];
        float f0 = bf2f((u16)v), f1 = bf2f((u16)(v >> 16));
        q00 = fmaf(av.x, f0, q00);  q01 = fmaf(av.x, f1, q01);
        q10 = fmaf(av.y, f0, q10);  q11 = fmaf(av.y, f1, q11);
        q20 = fmaf(av.z, f0, q20);  q21 = fmaf(av.z, f1, q21);
        q30 = fmaf(av.w, f0, q30);  q31 = fmaf(av.w, f1, q31);
    }
    if (lane < 56) {
        float* o0 = out + (size_t)g0 * NEWS_DIM + 2 * k;
        *(float2*)(o0)                = make_float2(q00, q01);
        *(float2*)(o0 + NEWS_DIM)     = make_float2(q10, q11);
        *(float2*)(o0 + 2 * NEWS_DIM) = make_float2(q20, q21);
        *(float2*)(o0 + 3 * NEWS_DIM) = make_float2(q30, q31);
    }
}

extern "C" void kernel_launch(void* const* d_in, const int* in_sizes, int n_in,
                              void* d_out, int out_size, void* d_ws, size_t ws_size,
                              hipStream_t stream) {
    const float* logv  = (const float*)d_in[0];  // (64,50,384) f32
    const int*   lmask = (const int*)d_in[1];    // (64,50) i32
    const float* newsv = (const float*)d_in[2];  // (64,64,384) f32
    const float* pos   = (const float*)d_in[3];  // (100,64) f32; row 0 == 0
    const float* W1    = (const float*)d_in[4];  // (256,896) f32
    const float* b1    = (const float*)d_in[5];  // (256,) f32
    const float* w2    = (const float*)d_in[6];  // (1,256) f32
    // b2 unused (softmax-invariant shift)

    float* out = (float*)d_out;                  // [user_log | nf], f32
    float* nf  = out + (size_t)B_ * NN_ * NEWS_DIM;

    // d_ws ~256 MiB. Byte offsets, 16B aligned:
    char* ws = (char*)d_ws;
    u16*   lf_bf = (u16*)(ws + 0);               // 3200x448 bf16  (2,867,200 B)
    u16*   Wbf   = (u16*)(ws + 2867200);         // 256x896 bf16   (458,752 B)
    u16*   nv_bf = (u16*)(ws + 3325952);         // 4096x384 bf16  (3,145,728 B)
    float* pn    = (float*)(ws + 6471680);       // 4096x256 f32   (4,194,304 B)
    float* plT   = (float*)(ws + 10665984);      // 64x256x50 f32  (3,276,800 B)

    prep_k    <<<3416, 256, 0, stream>>>(W1, newsv, logv, pos,
                                         Wbf, nv_bf, lf_bf, nf);
    gemm_k    <<<1824, 64, 0, stream>>>(nv_bf, lf_bf, Wbf, b1, pn, plT);
    attn_out_k<<<1024, 256, 0, stream>>>(pn, plT, w2, lmask, lf_bf, out);
}

// Round 10
// 123.475 us; speedup vs baseline: 2.8709x; 1.0066x over previous
//
#include <hip/hip_runtime.h>
#include <math.h>

typedef unsigned short u16;
typedef unsigned int   u32;

#define B_       64
#define NN_      64
#define HL_      50
#define IN_DIM   384
#define POS_DIM  64
#define ATT_DIM  256
#define NEWS_DIM 448   // IN_DIM + POS_DIM

typedef __attribute__((ext_vector_type(8))) short short8;   // bf16x8 MFMA frag
typedef __attribute__((ext_vector_type(4))) float f32x4;    // MFMA acc

#if __has_builtin(__builtin_amdgcn_exp2f)
#define EXP2F(x) __builtin_amdgcn_exp2f(x)
#else
#define EXP2F(x) exp2f(x)
#endif
#if __has_builtin(__builtin_amdgcn_rcpf)
#define RCPF(x) __builtin_amdgcn_rcpf(x)
#else
#define RCPF(x) (1.0f/(x))
#endif

__device__ __forceinline__ u16 f2bf(float f) {
    union { float f; u32 i; } v; v.f = f;
    u32 r = v.i + 0x7fffu + ((v.i >> 16) & 1u);   // RNE
    return (u16)(r >> 16);
}
__device__ __forceinline__ float bf2f(u16 u) {
    union { u32 i; float f; } v; v.i = ((u32)u) << 16; return v.f;
}
__device__ __forceinline__ uint2 pack4(float4 v) {
    return make_uint2((u32)f2bf(v.x) | ((u32)f2bf(v.y) << 16),
                      (u32)f2bf(v.z) | ((u32)f2bf(v.w) << 16));
}
// tanh(x) = 1 - 2/(1+2^(x*2*log2e)); v_exp+v_rcp saturate correctly at +-inf.
__device__ __forceinline__ float fast_tanh(float x) {
    float e = EXP2F(x * 2.88539008f);
    return 1.0f - 2.0f * RCPF(1.0f + e);
}

// ---------------- K0: bf16-convert W1/newsv/lf into ws; nf (f32) -> d_out.
// BYTE-IDENTICAL to R4 (XCD-aligned segments).
__global__ __launch_bounds__(256) void prep_k(
    const float* __restrict__ W1, const float* __restrict__ newsv,
    const float* __restrict__ logv, const float* __restrict__ pos,
    u16* __restrict__ Wbf, u16* __restrict__ nv_bf, u16* __restrict__ lf_bf,
    float* __restrict__ nf)
{
    u32 bid = blockIdx.x, tid = threadIdx.x;
    if (bid < 2936u) {
        u32 x = bid & 7u, j = bid >> 3;
        if (j < 192u) {            // newsv rows [512x, 512x+512) -> nv_bf + nf
            u32 idx = j * 256u + tid;              // < 49152
            u32 r = 512u * x + idx / 96u, d4 = idx % 96u;
            float4 v = *(const float4*)(newsv + (size_t)r * IN_DIM + d4 * 4u);
            *(uint2*)(nv_bf + (size_t)r * IN_DIM + d4 * 4u) = pack4(v);
            *(float4*)(nf + (size_t)r * NEWS_DIM + d4 * 4u) = v;
        } else if (j < 342u) {     // logv rows [400x, 400x+400) -> lf_bf head
            u32 idx = (j - 192u) * 256u + tid;     // < 38400
            u32 r = 400u * x + idx / 96u, d4 = idx % 96u;
            float4 v = *(const float4*)(logv + (size_t)r * IN_DIM + d4 * 4u);
            *(uint2*)(lf_bf + (size_t)r * NEWS_DIM + d4 * 4u) = pack4(v);
        } else {                   // pos tail, lf rows [400x, 400x+400)
            u32 idx = (j - 342u) * 256u + tid;     // < 6400
            u32 r = 400u * x + idx / 16u, d4 = idx % 16u;
            u32 h = r % HL_;
            float4 v = *(const float4*)(pos + (size_t)(1u + h) * POS_DIM + d4 * 4u);
            *(uint2*)(lf_bf + (size_t)r * NEWS_DIM + IN_DIM + d4 * 4u) = pack4(v);
        }
        return;
    }
    bid -= 2936u;
    if (bid < 224u) {              // W1 -> Wbf (read-shared; placement moot)
        u32 i = bid * 256u + tid;
        float4 v = *(const float4*)(W1 + (size_t)i * 4u);
        *(uint2*)(Wbf + (size_t)i * 4u) = pack4(v);
        return;
    }
    bid -= 224u;
    {                              // nf zero tail (no downstream reader)
        u32 i = bid * 256u + tid;  // < 65536
        u32 r = i / 16u, d4 = i % 16u;
        *(float4*)(nf + (size_t)r * NEWS_DIM + IN_DIM + d4 * 4u) =
            make_float4(0.f, 0.f, 0.f, 0.f);
    }
}

// ---------------- K1: fused NT GEMMs, 16x64-per-wave tiles.
// BYTE-IDENTICAL to R4.
__global__ __launch_bounds__(64) void gemm_k(
    const u16* __restrict__ nv_bf, const u16* __restrict__ lf_bf,
    const u16* __restrict__ Wbf, const float* __restrict__ b1,
    float* __restrict__ pn, float* __restrict__ plT)
{
    int bid = blockIdx.x;          // 1824 = 8*228
    int lane = threadIdx.x;
    int m = lane & 15, q = lane >> 4;
    int x = bid & 7, j = bid >> 3; // j in [0,228)
    bool is_pn = j < 128;
    int r0, c0, lda, koff, klen;
    const u16* A;
    if (is_pn) {                   // 16 tiles per b: 4 row-bands x 4 col-tiles
        int b = x * 8 + (j >> 4);
        r0 = b * 64 + ((j >> 2) & 3) * 16;
        c0 = (j & 3) * 64;
        A = nv_bf; lda = IN_DIM;   koff = 0;        klen = IN_DIM;
    } else {                       // 100 tiles: 25 row-bands x 4 col-tiles
        int j2 = j - 128;
        r0 = 400 * x + (j2 >> 2) * 16;
        c0 = (j2 & 3) * 64;
        A = lf_bf; lda = NEWS_DIM; koff = NEWS_DIM; klen = NEWS_DIM;
    }

    f32x4 acc[4];
#pragma unroll
    for (int b = 0; b < 4; b++) acc[b] = (f32x4){0.f, 0.f, 0.f, 0.f};

    const u16* Ap = A + (size_t)(r0 + m) * lda + q * 8;
    const u16* Wp = Wbf + (size_t)(c0 + m) * (2 * NEWS_DIM) + koff + q * 8;

    for (int k = 0; k < klen; k += 32) {
        short8 af, wf[4];
        af = *(const short8*)(Ap + k);
#pragma unroll
        for (int ct = 0; ct < 4; ct++) wf[ct] = *(const short8*)(Wp + ct * 16 * (2 * NEWS_DIM) + k);
#pragma unroll
        for (int ct = 0; ct < 4; ct++)
            acc[ct] = __builtin_amdgcn_mfma_f32_16x16x32_bf16(af, wf[ct], acc[ct], 0, 0, 0);
    }
    // C/D layout: col = lane&15, row = (lane>>4)*4 + i  [m89]
#pragma unroll
    for (int ct = 0; ct < 4; ct++)
#pragma unroll
        for (int i = 0; i < 4; i++) {
            int gr = r0 + q * 4 + i;
            int gc = c0 + ct * 16 + m;
            float v = acc[ct][i];
            if (is_pn) {
                pn[(size_t)gr * ATT_DIM + gc] = v + b1[gc];
            } else {
                int bb = gr / HL_, hh = gr - bb * HL_;
                plT[(size_t)(bb * ATT_DIM + gc) * HL_ + hh] = v;
            }
        }
}

// ---------------- K2: FUSED logits -> masked softmax -> out = attn x lf.
// R20: R9's reuse structure + LDS-STAGED pl (the R7 lesson applied right:
// a 16-a chunk of plT for one b is 800 CONTIGUOUS floats, so stage it
// with ~3.2 coalesced float4 loads + conflict-free ds_read, instead of 64
// scalar 4B loads/wave). Hand-pipelined: chunk c+1's global loads issue
// before chunk c's compute (3600cy tanh hides L2 latency). Phase-1 VMEM
// 64 -> 16 instr/wave. Tanh order unchanged -> logits bit-identical to R9.
// LDS 17.8KB/block -> still 4 blocks/CU.
__global__ __launch_bounds__(256) void attn_out_k(
    const float* __restrict__ pn, const float* __restrict__ plT,
    const float* __restrict__ w2, const int* __restrict__ lmask,
    const u16* __restrict__ lf_bf, float* __restrict__ out)
{
    __shared__ float pl_s[4][800];             // per-wave 16-a chunk  12.8KB
    __shared__ float part[4][4][64];           // [a-quarter][n][h]     4KB
    __shared__ float at4[64][4];               // [h][n] attn weights   1KB
    int lane = threadIdx.x & 63;
    int wid = __builtin_amdgcn_readfirstlane((int)(threadIdx.x >> 6)); // 0..3
    // XCD-clustered map: XCD x owns b in [8x,8x+8); 16 n-quads per b.
    int x     = blockIdx.x & 7;
    int local = blockIdx.x >> 3;               // [0,128)
    int b     = x * 8 + (local >> 4);
    int n0    = (local & 15) * 4;              // n-quad base
    int g0    = b * 64 + n0;                   // first of 4 pn/out rows
    int n_hl  = (lane < HL_) ? lane : (HL_ - 1);

    // ---- phase 1: a-range [64*wid, +64), 4 chunks of 16 a (800 f32) ----
    int a0 = wid * 64;
    const float* pr0 = pn + (size_t)(g0 + 0) * ATT_DIM + a0;  // uniform
    const float* pr1 = pn + (size_t)(g0 + 1) * ATT_DIM + a0;
    const float* pr2 = pn + (size_t)(g0 + 2) * ATT_DIM + a0;
    const float* pr3 = pn + (size_t)(g0 + 3) * ATT_DIM + a0;
    const float* w2o = w2 + a0;
    const float4* src4 = (const float4*)(plT + ((size_t)b * ATT_DIM + a0) * HL_);
    float* pls = pl_s[wid];

    float c0 = 0.f, c1 = 0.f, c2 = 0.f, c3 = 0.f;   // chain A per n
    float d0 = 0.f, d1 = 0.f, d2 = 0.f, d3 = 0.f;   // chain B per n

    // prologue: loads for chunk 0 (200 float4 per chunk; lane covers
    // idx {l, l+64, l+128} + tail l+192 for l<8)
    float4 s0 = src4[lane];
    float4 s1 = src4[lane + 64];
    float4 s2 = src4[lane + 128];
    float4 s3 = (lane < 8) ? src4[lane + 192] : make_float4(0.f, 0.f, 0.f, 0.f);

    for (int c = 0; c < 4; c++) {
        // stage current chunk to LDS
        *(float4*)&pls[4 * lane]         = s0;
        *(float4*)&pls[4 * (lane + 64)]  = s1;
        *(float4*)&pls[4 * (lane + 128)] = s2;
        if (lane < 8) *(float4*)&pls[4 * (lane + 192)] = s3;
        // issue next chunk's loads (latency hides under compute below)
        if (c < 3) {
            const float4* nx = src4 + (c + 1) * 200;
            s0 = nx[lane];
            s1 = nx[lane + 64];
            s2 = nx[lane + 128];
            if (lane < 8) s3 = nx[lane + 192];
        }
        // compute 16 a's of this chunk from LDS
        int ab = c * 16;
#pragma unroll 4
        for (int i = 0; i < 16; i += 4) {
            int a = ab + i;
            float4 w4 = *(const float4*)(w2o + a);      // uniform -> s_load
            float4 pA = *(const float4*)(pr0 + a);      // uniform -> s_load
            float4 pB = *(const float4*)(pr1 + a);
            float4 pC = *(const float4*)(pr2 + a);
            float4 pD = *(const float4*)(pr3 + a);
            float l0 = pls[(i + 0) * HL_ + n_hl];
            float l1 = pls[(i + 1) * HL_ + n_hl];
            float l2 = pls[(i + 2) * HL_ + n_hl];
            float l3 = pls[(i + 3) * HL_ + n_hl];
            c0 = __builtin_fmaf(fast_tanh(pA.x + l0), w4.x, c0);
            d0 = __builtin_fmaf(fast_tanh(pA.y + l1), w4.y, d0);
            c0 = __builtin_fmaf(fast_tanh(pA.z + l2), w4.z, c0);
            d0 = __builtin_fmaf(fast_tanh(pA.w + l3), w4.w, d0);
            c1 = __builtin_fmaf(fast_tanh(pB.x + l0), w4.x, c1);
            d1 = __builtin_fmaf(fast_tanh(pB.y + l1), w4.y, d1);
            c1 = __builtin_fmaf(fast_tanh(pB.z + l2), w4.z, c1);
            d1 = __builtin_fmaf(fast_tanh(pB.w + l3), w4.w, d1);
            c2 = __builtin_fmaf(fast_tanh(pC.x + l0), w4.x, c2);
            d2 = __builtin_fmaf(fast_tanh(pC.y + l1), w4.y, d2);
            c2 = __builtin_fmaf(fast_tanh(pC.z + l2), w4.z, c2);
            d2 = __builtin_fmaf(fast_tanh(pC.w + l3), w4.w, d2);
            c3 = __builtin_fmaf(fast_tanh(pD.x + l0), w4.x, c3);
            d3 = __builtin_fmaf(fast_tanh(pD.y + l1), w4.y, d3);
            c3 = __builtin_fmaf(fast_tanh(pD.z + l2), w4.z, c3);
            d3 = __builtin_fmaf(fast_tanh(pD.w + l3), w4.w, d3);
        }
    }
    part[wid][0][lane] = c0 + d0;
    part[wid][1][lane] = c1 + d1;
    part[wid][2][lane] = c2 + d2;
    part[wid][3][lane] = c3 + d3;
    __syncthreads();

    // ---- softmax: wave wid handles n = wid ----
    float acc = (part[0][wid][lane] + part[1][wid][lane])
              + (part[2][wid][lane] + part[3][wid][lane]);
    int mv = (lane < HL_) ? lmask[b * HL_ + lane] : 0;
    float logit = mv ? acc : -1e9f;            // b2 dropped: softmax-invariant
    float mx = logit;
#pragma unroll
    for (int o = 32; o > 0; o >>= 1) mx = fmaxf(mx, __shfl_xor(mx, o));
    float e = EXP2F((logit - mx) * 1.44269504f);   // masked lanes -> 0
    float s = e;
#pragma unroll
    for (int o = 32; o > 0; o >>= 1) s += __shfl_xor(s, o);
    at4[lane][wid] = e * RCPF(s);
    __syncthreads();

    // ---- phase 2: wave wid covers u32 range [56*wid, +56), 4 n's ----
    // (R9-proven; per-output h-order unchanged -> bit-identical)
    int l56 = (lane < 56) ? lane : 55;
    int k   = wid * 56 + l56;                  // u32 index in row of 224
    const u32* lfb32 = (const u32*)(lf_bf + (size_t)b * HL_ * NEWS_DIM);
    float q00 = 0.f, q01 = 0.f, q10 = 0.f, q11 = 0.f;
    float q20 = 0.f, q21 = 0.f, q30 = 0.f, q31 = 0.f;
    for (int h = 0; h < HL_; h++) {
        float4 av = *(const float4*)at4[h];    // LDS broadcast, 4 attn vals
        u32 v = lfb32[h * (NEWS_DIM / 2) + k];
        float f0 = bf2f((u16)v), f1 = bf2f((u16)(v >> 16));
        q00 = fmaf(av.x, f0, q00);  q01 = fmaf(av.x, f1, q01);
        q10 = fmaf(av.y, f0, q10);  q11 = fmaf(av.y, f1, q11);
        q20 = fmaf(av.z, f0, q20);  q21 = fmaf(av.z, f1, q21);
        q30 = fmaf(av.w, f0, q30);  q31 = fmaf(av.w, f1, q31);
    }
    if (lane < 56) {
        float* o0 = out + (size_t)g0 * NEWS_DIM + 2 * k;
        *(float2*)(o0)                = make_float2(q00, q01);
        *(float2*)(o0 + NEWS_DIM)     = make_float2(q10, q11);
        *(float2*)(o0 + 2 * NEWS_DIM) = make_float2(q20, q21);
        *(float2*)(o0 + 3 * NEWS_DIM) = make_float2(q30, q31);
    }
}

extern "C" void kernel_launch(void* const* d_in, const int* in_sizes, int n_in,
                              void* d_out, int out_size, void* d_ws, size_t ws_size,
                              hipStream_t stream) {
    const float* logv  = (const float*)d_in[0];  // (64,50,384) f32
    const int*   lmask = (const int*)d_in[1];    // (64,50) i32
    const float* newsv = (const float*)d_in[2];  // (64,64,384) f32
    const float* pos   = (const float*)d_in[3];  // (100,64) f32; row 0 == 0
    const float* W1    = (const float*)d_in[4];  // (256,896) f32
    const float* b1    = (const float*)d_in[5];  // (256,) f32
    const float* w2    = (const float*)d_in[6];  // (1,256) f32
    // b2 unused (softmax-invariant shift)

    float* out = (float*)d_out;                  // [user_log | nf], f32
    float* nf  = out + (size_t)B_ * NN_ * NEWS_DIM;

    // d_ws ~256 MiB. Byte offsets, 16B aligned:
    char* ws = (char*)d_ws;
    u16*   lf_bf = (u16*)(ws + 0);               // 3200x448 bf16  (2,867,200 B)
    u16*   Wbf   = (u16*)(ws + 2867200);         // 256x896 bf16   (458,752 B)
    u16*   nv_bf = (u16*)(ws + 3325952);         // 4096x384 bf16  (3,145,728 B)
    float* pn    = (float*)(ws + 6471680);       // 4096x256 f32   (4,194,304 B)
    float* plT   = (float*)(ws + 10665984);      // 64x256x50 f32  (3,276,800 B)

    prep_k    <<<3416, 256, 0, stream>>>(W1, newsv, logv, pos,
                                         Wbf, nv_bf, lf_bf, nf);
    gemm_k    <<<1824, 64, 0, stream>>>(nv_bf, lf_bf, Wbf, b1, pn, plT);
    attn_out_k<<<1024, 256, 0, stream>>>(pn, plT, w2, lmask, lf_bf, out);
}